// Round 1
// baseline (401.062 us; speedup 1.0000x reference)
//
#include <hip/hip_runtime.h>
#include <math.h>

// Problem constants
constexpr int NND = 8192;           // N nodes
constexpr int FD  = 512;            // features
constexpr int HD  = 128;            // hidden
constexpr int ED  = 262144;         // edges
constexpr long long NF_ = (long long)NND * FD;      // 4,194,304
constexpr long long NN_ = (long long)NND * NND;     // 67,108,864

// ---- order-preserving float <-> uint for atomic min/max ----
__device__ __forceinline__ unsigned fkey(float f) {
    unsigned b = __float_as_uint(f);
    return (b & 0x80000000u) ? ~b : (b | 0x80000000u);
}
__device__ __forceinline__ float fdec(unsigned k) {
    return (k & 0x80000000u) ? __uint_as_float(k ^ 0x80000000u)
                             : __uint_as_float(~k);
}

// ctrl layout (unsigned words in ws):
// [0]=min key, [1]=max key, [2]=cnt_unique, [3]=cnt_nonzero

// K_A: feature = masked x; zero the dense adj region; init counts/ctrl.
__global__ void kA_feature_zero_init(const float* __restrict__ x,
                                     const float* __restrict__ mask_u,
                                     float* __restrict__ out,
                                     int* __restrict__ counts,
                                     unsigned* __restrict__ ctrl) {
    long long gid = (long long)blockIdx.x * blockDim.x + threadIdx.x;
    if (gid < NND) counts[gid] = 0;
    if (gid == 0) { ctrl[0] = 0xFFFFFFFFu; ctrl[1] = 0u; ctrl[2] = 0u; ctrl[3] = 0u; }

    const long long NF4 = NF_ / 4, TOT4 = (NF_ + NN_) / 4;
    long long stride = (long long)gridDim.x * blockDim.x;

    // stride is a multiple of 128, so the column-quad index is per-thread constant
    int c4 = (int)(gid & 127);
    float kx = (mask_u[c4 * 4 + 0] < 0.2f) ? 0.f : 1.f;
    float ky = (mask_u[c4 * 4 + 1] < 0.2f) ? 0.f : 1.f;
    float kz = (mask_u[c4 * 4 + 2] < 0.2f) ? 0.f : 1.f;
    float kw = (mask_u[c4 * 4 + 3] < 0.2f) ? 0.f : 1.f;
    float4 z4 = make_float4(0.f, 0.f, 0.f, 0.f);

    for (long long i4 = gid; i4 < TOT4; i4 += stride) {
        if (i4 < NF4) {
            float4 xv = ((const float4*)x)[i4];
            float4 o;
            o.x = xv.x * kx; o.y = xv.y * ky; o.z = xv.z * kz; o.w = xv.w * kw;
            ((float4*)out)[i4] = o;
        } else {
            ((float4*)out)[i4] = z4;
        }
    }
}

// K_B: fp32 GEMM xw = x @ W_enc  (8192x512 @ 512x128), fused row-histogram.
// 256 blocks x 256 threads; block computes 32 rows x 128 cols; thread: 2x8.
__global__ __launch_bounds__(256) void kB_gemm_hist(const float* __restrict__ x,
                                                    const float* __restrict__ W,
                                                    float* __restrict__ xw,
                                                    const int* __restrict__ row,
                                                    int* __restrict__ counts) {
    int gid = blockIdx.x * 256 + threadIdx.x;
#pragma unroll
    for (int i = 0; i < 4; ++i)
        atomicAdd(&counts[row[gid + i * 65536]], 1);

    int tx = threadIdx.x & 15, ty = threadIdx.x >> 4;
    int m0 = blockIdx.x * 32 + ty * 2;
    const float* xr0 = x + (long long)m0 * FD;
    const float* xr1 = xr0 + FD;
    float acc0[8] = {0, 0, 0, 0, 0, 0, 0, 0};
    float acc1[8] = {0, 0, 0, 0, 0, 0, 0, 0};
#pragma unroll 4
    for (int k = 0; k < FD; ++k) {
        float a0 = xr0[k], a1 = xr1[k];
        const float* wk = W + k * HD + tx * 8;
        float4 b0 = *(const float4*)wk;
        float4 b1 = *(const float4*)(wk + 4);
        float b[8] = {b0.x, b0.y, b0.z, b0.w, b1.x, b1.y, b1.z, b1.w};
#pragma unroll
        for (int j = 0; j < 8; ++j) {
            acc0[j] = fmaf(a0, b[j], acc0[j]);
            acc1[j] = fmaf(a1, b[j], acc1[j]);
        }
    }
    float4* o0 = (float4*)(xw + (long long)m0 * HD + tx * 8);
    float4* o1 = (float4*)(xw + (long long)(m0 + 1) * HD + tx * 8);
    o0[0] = make_float4(acc0[0], acc0[1], acc0[2], acc0[3]);
    o0[1] = make_float4(acc0[4], acc0[5], acc0[6], acc0[7]);
    o1[0] = make_float4(acc1[0], acc1[1], acc1[2], acc1[3]);
    o1[1] = make_float4(acc1[4], acc1[5], acc1[6], acc1[7]);
}

// K_C: exclusive scan of per-row counts -> row_start[N+1], cursor[N]. 1 block.
__global__ __launch_bounds__(1024) void kC_scan(const int* __restrict__ counts,
                                                int* __restrict__ row_start,
                                                int* __restrict__ cursor) {
    __shared__ int s[1024];
    int t = threadIdx.x;
    int c[8];
    int sum = 0;
#pragma unroll
    for (int j = 0; j < 8; ++j) { c[j] = counts[t * 8 + j]; sum += c[j]; }
    s[t] = sum;
    __syncthreads();
    for (int d = 1; d < 1024; d <<= 1) {
        int add = (t >= d) ? s[t - d] : 0;
        __syncthreads();
        s[t] += add;
        __syncthreads();
    }
    int run = (t == 0) ? 0 : s[t - 1];
#pragma unroll
    for (int j = 0; j < 8; ++j) {
        row_start[t * 8 + j] = run;
        cursor[t * 8 + j] = run;
        run += c[j];
    }
    if (t == 1023) row_start[8192] = run;
}

// K_D: bucket edges by row (order within a row is arbitrary).
__global__ void kD_scatter(const int* __restrict__ row, const int* __restrict__ col,
                           int* __restrict__ cursor, int* __restrict__ scol) {
    int e = blockIdx.x * 256 + threadIdx.x;
    int r = row[e];
    int pos = atomicAdd(&cursor[r], 1);
    scol[pos] = col[e];
}

// K_E: agg[i] = sum_{edges of i} xw[col]; relu; u=agg@W1, v=agg@W2.
// One block (128 thr) per node row.
__global__ __launch_bounds__(128) void kE_spmm_uv(const float* __restrict__ xw,
                                                  const int* __restrict__ row_start,
                                                  const int* __restrict__ scol,
                                                  const float* __restrict__ Wedge,
                                                  float* __restrict__ u,
                                                  float* __restrict__ v) {
    int i = blockIdx.x, t = threadIdx.x;
    int s0 = row_start[i], s1 = row_start[i + 1];
    float acc = 0.f;
    int j = s0;
    for (; j + 4 <= s1; j += 4) {
        int c0 = scol[j], c1 = scol[j + 1], c2 = scol[j + 2], c3 = scol[j + 3];
        float v0 = xw[(long long)c0 * HD + t];
        float v1 = xw[(long long)c1 * HD + t];
        float v2 = xw[(long long)c2 * HD + t];
        float v3 = xw[(long long)c3 * HD + t];
        acc += v0; acc += v1; acc += v2; acc += v3;
    }
    for (; j < s1; ++j) acc += xw[(long long)scol[j] * HD + t];
    acc = fmaxf(acc, 0.f);

    float up = acc * Wedge[t];
    float vp = acc * Wedge[HD + t];
#pragma unroll
    for (int off = 32; off > 0; off >>= 1) {
        up += __shfl_down(up, off);
        vp += __shfl_down(vp, off);
    }
    __shared__ float su[2], sv[2];
    int wid = t >> 6;
    if ((t & 63) == 0) { su[wid] = up; sv[wid] = vp; }
    __syncthreads();
    if (t == 0) { u[i] = su[0] + su[1]; v[i] = sv[0] + sv[1]; }
}

// K_F: edge_logits + global min/max (ordered-uint atomics).
__global__ void kF_elog(const int* __restrict__ row, const int* __restrict__ col,
                        const float* __restrict__ u, const float* __restrict__ v,
                        const float* __restrict__ b_edge,
                        float* __restrict__ elog, unsigned* __restrict__ ctrl) {
    int e = blockIdx.x * 256 + threadIdx.x;
    float el = u[row[e]] + v[col[e]] + b_edge[0];
    elog[e] = el;
    float mn = el, mx = el;
#pragma unroll
    for (int off = 32; off > 0; off >>= 1) {
        mn = fminf(mn, __shfl_xor(mn, off));
        mx = fmaxf(mx, __shfl_xor(mx, off));
    }
    if ((threadIdx.x & 63) == 0) {
        atomicMin(&ctrl[0], fkey(mn));
        atomicMax(&ctrl[1], fkey(mx));
    }
}

// K_G: per-edge hard bit + winner election (last-edge-wins via max(e+1)).
__global__ void kG_hard(const int* __restrict__ row, const int* __restrict__ col,
                        const float* __restrict__ elog, const float* __restrict__ noise,
                        const unsigned* __restrict__ ctrl,
                        unsigned char* __restrict__ hard, int* __restrict__ adjI) {
    int e = blockIdx.x * 256 + threadIdx.x;
    float lo = fdec(ctrl[0]);
    float hi = fdec(ctrl[1]);
    float kk = 0.3f / (hi - lo);                // ub=0.3, lb=0
    float p = kk * (elog[e] - lo);
    float lp = logf(p + 1e-10f) - log1pf(1e-10f - p);
    long long cell = (long long)row[e] * NND + col[e];
    float nz = noise[cell];
    float lg = logf(nz) - log1pf(-nz);
    int h = ((lp + lg) > 0.f) ? 1 : 0;          // round(sigmoid(z/T)) == (z>0)
    hard[e] = (unsigned char)h;
    atomicMax(&adjI[cell], e + 1);
}

// K_H: winner writes adj value; ballot-count unique cells & nonzero cells.
__global__ void kH_write(const int* __restrict__ row, const int* __restrict__ col,
                         const unsigned char* __restrict__ hard,
                         int* __restrict__ adjI, unsigned* __restrict__ ctrl) {
    int e = blockIdx.x * 256 + threadIdx.x;
    long long cell = (long long)row[e] * NND + col[e];
    int w = adjI[cell];
    bool win = (w == e + 1);
    bool nzv = win && (hard[e] == 0);
    if (win) ((float*)adjI)[cell] = nzv ? 1.0f : 0.0f;
    unsigned long long mw = __ballot(win);
    unsigned long long mz = __ballot(nzv);
    if ((threadIdx.x & 63) == 0) {
        atomicAdd(&ctrl[2], (unsigned)__popcll(mw));
        atomicAdd(&ctrl[3], (unsigned)__popcll(mz));
    }
}

// K_I: adj_aug_rate scalar.
__global__ void kI_rate(const unsigned* __restrict__ ctrl, float* __restrict__ out) {
    out[0] = (float)ctrl[3] / (float)ctrl[2];
}

extern "C" void kernel_launch(void* const* d_in, const int* in_sizes, int n_in,
                              void* d_out, int out_size, void* d_ws, size_t ws_size,
                              hipStream_t stream) {
    const float* x     = (const float*)d_in[0];
    const int*   row   = (const int*)d_in[1];
    const int*   col   = (const int*)d_in[2];
    const float* Wenc  = (const float*)d_in[3];
    const float* Wedge = (const float*)d_in[4];
    const float* bedge = (const float*)d_in[5];
    const float* noise = (const float*)d_in[6];
    const float* masku = (const float*)d_in[7];
    float* out = (float*)d_out;

    // workspace layout (~6.5 MB)
    char* ws = (char*)d_ws;
    float* xw        = (float*)(ws);                    // 4 MB
    float* elog      = (float*)(ws + 4194304);          // 1 MB
    float* u         = (float*)(ws + 5242880);          // 32 KB
    float* v         = (float*)(ws + 5275648);          // 32 KB
    int*   row_start = (int*)  (ws + 5308416);          // 32772 B (res 36864)
    int*   cursor    = (int*)  (ws + 5345280);          // 32 KB
    int*   scol      = (int*)  (ws + 5378048);          // 1 MB
    int*   counts    = (int*)  (ws + 6426624);          // 32 KB
    unsigned char* hard = (unsigned char*)(ws + 6459392); // 256 KB
    unsigned* ctrl   = (unsigned*)(ws + 6721536);       // 64 B

    float* adjF = out + NF_;

    kA_feature_zero_init<<<2048, 256, 0, stream>>>(x, masku, out, counts, ctrl);
    kB_gemm_hist<<<256, 256, 0, stream>>>(x, Wenc, xw, row, counts);
    kC_scan<<<1, 1024, 0, stream>>>(counts, row_start, cursor);
    kD_scatter<<<1024, 256, 0, stream>>>(row, col, cursor, scol);
    kE_spmm_uv<<<8192, 128, 0, stream>>>(xw, row_start, scol, Wedge, u, v);
    kF_elog<<<1024, 256, 0, stream>>>(row, col, u, v, bedge, elog, ctrl);
    kG_hard<<<1024, 256, 0, stream>>>(row, col, elog, noise, ctrl, hard, (int*)adjF);
    kH_write<<<1024, 256, 0, stream>>>(row, col, hard, (int*)adjF, ctrl);
    kI_rate<<<1, 1, 0, stream>>>(ctrl, out + NF_ + NN_);
}

// Round 2
// 372.048 us; speedup vs baseline: 1.0780x; 1.0780x over previous
//
#include <hip/hip_runtime.h>
#include <math.h>

// Problem constants
constexpr int NND = 8192;           // N nodes
constexpr int FD  = 512;            // features
constexpr int HD  = 128;            // hidden
constexpr int ED  = 262144;         // edges
constexpr long long NF_ = (long long)NND * FD;      // 4,194,304
constexpr long long NN_ = (long long)NND * NND;     // 67,108,864
constexpr long long NF4 = NF_ / 4;                  // 1,048,576 quads
constexpr int GEMM_BLOCKS = 512;                    // 16 rows each
constexpr int FILL_BLOCKS = 4096;                   // 1,048,576 threads

// ---- order-preserving float <-> uint for atomic min/max ----
__device__ __forceinline__ unsigned fkey(float f) {
    unsigned b = __float_as_uint(f);
    return (b & 0x80000000u) ? ~b : (b | 0x80000000u);
}
__device__ __forceinline__ float fdec(unsigned k) {
    return (k & 0x80000000u) ? __uint_as_float(k ^ 0x80000000u)
                             : __uint_as_float(~k);
}

// ctrl: [0]=min key, [1]=max key, [2]=cnt_unique, [3]=cnt_nonzero

// K0: zero counts, init ctrl.
__global__ void k0_init(int* __restrict__ counts, unsigned* __restrict__ ctrl) {
    int t = blockIdx.x * 256 + threadIdx.x;
    if (t < NND) counts[t] = 0;
    if (t == 0) { ctrl[0] = 0xFFFFFFFFu; ctrl[1] = 0u; ctrl[2] = 0u; ctrl[3] = 0u; }
}

// K1 mega: blocks [0,512) = fp32 GEMM xw = x@W_enc + edge histogram;
//          blocks [512,4608) = feature mask write + dense adj zero-fill.
// GEMM blocks first in dispatch order so compute overlaps the HBM fill.
__global__ __launch_bounds__(256) void k1_mega(const float* __restrict__ x,
                                               const float* __restrict__ W,
                                               const float* __restrict__ mask_u,
                                               const int* __restrict__ row,
                                               float* __restrict__ out,
                                               float* __restrict__ xw,
                                               int* __restrict__ counts) {
    int tid = threadIdx.x;
    if (blockIdx.x < GEMM_BLOCKS) {
        int bid = blockIdx.x;
        // edge histogram (counts pre-zeroed by k0)
        int g2 = bid * 256 + tid;
        atomicAdd(&counts[row[g2]], 1);
        atomicAdd(&counts[row[g2 + 131072]], 1);

        // GEMM: block = 16 rows x 128 cols; thread = 2 rows x 4 cols.
        int tx = tid & 31, ty = tid >> 5;
        int m0 = bid * 16 + ty * 2;
        const float* xr0 = x + (long long)m0 * FD;
        const float* xr1 = xr0 + FD;
        float a0[4] = {0.f, 0.f, 0.f, 0.f};
        float a1[4] = {0.f, 0.f, 0.f, 0.f};
#pragma unroll 4
        for (int k = 0; k < FD; ++k) {
            float s0 = xr0[k], s1 = xr1[k];
            float4 b = *(const float4*)(W + k * HD + tx * 4);
            a0[0] = fmaf(s0, b.x, a0[0]);
            a0[1] = fmaf(s0, b.y, a0[1]);
            a0[2] = fmaf(s0, b.z, a0[2]);
            a0[3] = fmaf(s0, b.w, a0[3]);
            a1[0] = fmaf(s1, b.x, a1[0]);
            a1[1] = fmaf(s1, b.y, a1[1]);
            a1[2] = fmaf(s1, b.z, a1[2]);
            a1[3] = fmaf(s1, b.w, a1[3]);
        }
        *(float4*)(xw + (long long)m0 * HD + tx * 4) =
            make_float4(a0[0], a0[1], a0[2], a0[3]);
        *(float4*)(xw + (long long)(m0 + 1) * HD + tx * 4) =
            make_float4(a1[0], a1[1], a1[2], a1[3]);
    } else {
        // fill path: thread gid in [0, 1048576)
        long long gid = (long long)(blockIdx.x - GEMM_BLOCKS) * 256 + tid;
        // feature quad (columns (gid&127)*4 .. +3)
        int c4 = (int)(gid & 127) * 4;
        float kx = (mask_u[c4 + 0] < 0.2f) ? 0.f : 1.f;
        float ky = (mask_u[c4 + 1] < 0.2f) ? 0.f : 1.f;
        float kz = (mask_u[c4 + 2] < 0.2f) ? 0.f : 1.f;
        float kw = (mask_u[c4 + 3] < 0.2f) ? 0.f : 1.f;
        float4 xv = ((const float4*)x)[gid];
        float4 o;
        o.x = xv.x * kx; o.y = xv.y * ky; o.z = xv.z * kz; o.w = xv.w * kw;
        float4* oq = (float4*)out;
        oq[gid] = o;
        // exactly 16 zero quads covering the dense adj region
        float4 z = make_float4(0.f, 0.f, 0.f, 0.f);
#pragma unroll
        for (int it = 1; it <= 16; ++it)
            oq[gid + (long long)it * NF4] = z;
    }
}

// K_C: exclusive scan of per-row counts -> row_start[N+1], cursor[N]. 1 block.
__global__ __launch_bounds__(1024) void kC_scan(const int* __restrict__ counts,
                                                int* __restrict__ row_start,
                                                int* __restrict__ cursor) {
    __shared__ int s[1024];
    int t = threadIdx.x;
    int c[8];
    int sum = 0;
#pragma unroll
    for (int j = 0; j < 8; ++j) { c[j] = counts[t * 8 + j]; sum += c[j]; }
    s[t] = sum;
    __syncthreads();
    for (int d = 1; d < 1024; d <<= 1) {
        int add = (t >= d) ? s[t - d] : 0;
        __syncthreads();
        s[t] += add;
        __syncthreads();
    }
    int run = (t == 0) ? 0 : s[t - 1];
#pragma unroll
    for (int j = 0; j < 8; ++j) {
        row_start[t * 8 + j] = run;
        cursor[t * 8 + j] = run;
        run += c[j];
    }
    if (t == 1023) row_start[8192] = run;
}

// K_D: bucket edges by row (order within a row is arbitrary).
__global__ void kD_scatter(const int* __restrict__ row, const int* __restrict__ col,
                           int* __restrict__ cursor, int* __restrict__ scol) {
    int e = blockIdx.x * 256 + threadIdx.x;
    int r = row[e];
    int pos = atomicAdd(&cursor[r], 1);
    scol[pos] = col[e];
}

// K_E: agg[i] = sum_{edges of i} xw[col]; relu; u=agg@W1, v=agg@W2.
__global__ __launch_bounds__(128) void kE_spmm_uv(const float* __restrict__ xw,
                                                  const int* __restrict__ row_start,
                                                  const int* __restrict__ scol,
                                                  const float* __restrict__ Wedge,
                                                  float* __restrict__ u,
                                                  float* __restrict__ v) {
    int i = blockIdx.x, t = threadIdx.x;
    int s0 = row_start[i], s1 = row_start[i + 1];
    float acc = 0.f;
    int j = s0;
    for (; j + 4 <= s1; j += 4) {
        int c0 = scol[j], c1 = scol[j + 1], c2 = scol[j + 2], c3 = scol[j + 3];
        float v0 = xw[(long long)c0 * HD + t];
        float v1 = xw[(long long)c1 * HD + t];
        float v2 = xw[(long long)c2 * HD + t];
        float v3 = xw[(long long)c3 * HD + t];
        acc += v0; acc += v1; acc += v2; acc += v3;
    }
    for (; j < s1; ++j) acc += xw[(long long)scol[j] * HD + t];
    acc = fmaxf(acc, 0.f);

    float up = acc * Wedge[t];
    float vp = acc * Wedge[HD + t];
#pragma unroll
    for (int off = 32; off > 0; off >>= 1) {
        up += __shfl_down(up, off);
        vp += __shfl_down(vp, off);
    }
    __shared__ float su[2], sv[2];
    int wid = t >> 6;
    if ((t & 63) == 0) { su[wid] = up; sv[wid] = vp; }
    __syncthreads();
    if (t == 0) { u[i] = su[0] + su[1]; v[i] = sv[0] + sv[1]; }
}

// K_F: edge_logits + global min/max (ordered-uint atomics).
__global__ void kF_elog(const int* __restrict__ row, const int* __restrict__ col,
                        const float* __restrict__ u, const float* __restrict__ v,
                        const float* __restrict__ b_edge,
                        float* __restrict__ elog, unsigned* __restrict__ ctrl) {
    int e = blockIdx.x * 256 + threadIdx.x;
    float el = u[row[e]] + v[col[e]] + b_edge[0];
    elog[e] = el;
    float mn = el, mx = el;
#pragma unroll
    for (int off = 32; off > 0; off >>= 1) {
        mn = fminf(mn, __shfl_xor(mn, off));
        mx = fmaxf(mx, __shfl_xor(mx, off));
    }
    if ((threadIdx.x & 63) == 0) {
        atomicMin(&ctrl[0], fkey(mn));
        atomicMax(&ctrl[1], fkey(mx));
    }
}

// K_G: per-edge hard bit + winner election (last-edge-wins via max(e+1)).
__global__ void kG_hard(const int* __restrict__ row, const int* __restrict__ col,
                        const float* __restrict__ elog, const float* __restrict__ noise,
                        const unsigned* __restrict__ ctrl,
                        unsigned char* __restrict__ hard, int* __restrict__ adjI) {
    int e = blockIdx.x * 256 + threadIdx.x;
    float lo = fdec(ctrl[0]);
    float hi = fdec(ctrl[1]);
    float kk = 0.3f / (hi - lo);                // ub=0.3, lb=0
    float p = kk * (elog[e] - lo);
    float lp = logf(p + 1e-10f) - log1pf(1e-10f - p);
    long long cell = (long long)row[e] * NND + col[e];
    float nz = noise[cell];
    float lg = logf(nz) - log1pf(-nz);
    int h = ((lp + lg) > 0.f) ? 1 : 0;          // round(sigmoid(z/T)) == (z>0)
    hard[e] = (unsigned char)h;
    atomicMax(&adjI[cell], e + 1);
}

// K_H: winner writes adj value; ballot-count unique cells & nonzero cells.
__global__ void kH_write(const int* __restrict__ row, const int* __restrict__ col,
                         const unsigned char* __restrict__ hard,
                         int* __restrict__ adjI, unsigned* __restrict__ ctrl) {
    int e = blockIdx.x * 256 + threadIdx.x;
    long long cell = (long long)row[e] * NND + col[e];
    int w = adjI[cell];
    bool win = (w == e + 1);
    bool nzv = win && (hard[e] == 0);
    if (win) ((float*)adjI)[cell] = nzv ? 1.0f : 0.0f;
    unsigned long long mw = __ballot(win);
    unsigned long long mz = __ballot(nzv);
    if ((threadIdx.x & 63) == 0) {
        atomicAdd(&ctrl[2], (unsigned)__popcll(mw));
        atomicAdd(&ctrl[3], (unsigned)__popcll(mz));
    }
}

// K_I: adj_aug_rate scalar.
__global__ void kI_rate(const unsigned* __restrict__ ctrl, float* __restrict__ out) {
    out[0] = (float)ctrl[3] / (float)ctrl[2];
}

extern "C" void kernel_launch(void* const* d_in, const int* in_sizes, int n_in,
                              void* d_out, int out_size, void* d_ws, size_t ws_size,
                              hipStream_t stream) {
    const float* x     = (const float*)d_in[0];
    const int*   row   = (const int*)d_in[1];
    const int*   col   = (const int*)d_in[2];
    const float* Wenc  = (const float*)d_in[3];
    const float* Wedge = (const float*)d_in[4];
    const float* bedge = (const float*)d_in[5];
    const float* noise = (const float*)d_in[6];
    const float* masku = (const float*)d_in[7];
    float* out = (float*)d_out;

    // workspace layout (~6.5 MB)
    char* ws = (char*)d_ws;
    float* xw        = (float*)(ws);                    // 4 MB
    float* elog      = (float*)(ws + 4194304);          // 1 MB
    float* u         = (float*)(ws + 5242880);          // 32 KB
    float* v         = (float*)(ws + 5275648);          // 32 KB
    int*   row_start = (int*)  (ws + 5308416);          // 32772 B (res 36864)
    int*   cursor    = (int*)  (ws + 5345280);          // 32 KB
    int*   scol      = (int*)  (ws + 5378048);          // 1 MB
    int*   counts    = (int*)  (ws + 6426624);          // 32 KB
    unsigned char* hard = (unsigned char*)(ws + 6459392); // 256 KB
    unsigned* ctrl   = (unsigned*)(ws + 6721536);       // 64 B

    float* adjF = out + NF_;

    k0_init<<<32, 256, 0, stream>>>(counts, ctrl);
    k1_mega<<<GEMM_BLOCKS + FILL_BLOCKS, 256, 0, stream>>>(x, Wenc, masku, row,
                                                           out, xw, counts);
    kC_scan<<<1, 1024, 0, stream>>>(counts, row_start, cursor);
    kD_scatter<<<1024, 256, 0, stream>>>(row, col, cursor, scol);
    kE_spmm_uv<<<8192, 128, 0, stream>>>(xw, row_start, scol, Wedge, u, v);
    kF_elog<<<1024, 256, 0, stream>>>(row, col, u, v, bedge, elog, ctrl);
    kG_hard<<<1024, 256, 0, stream>>>(row, col, elog, noise, ctrl, hard, (int*)adjF);
    kH_write<<<1024, 256, 0, stream>>>(row, col, hard, (int*)adjF, ctrl);
    kI_rate<<<1, 1, 0, stream>>>(ctrl, out + NF_ + NN_);
}